// Round 1
// baseline (1054.160 us; speedup 1.0000x reference)
//
#include <hip/hip_runtime.h>
#include <hip/hip_fp16.h>
#include <hip/hip_cooperative_groups.h>

namespace cg = cooperative_groups;

typedef __attribute__((ext_vector_type(8))) short bf16x8;
typedef __attribute__((ext_vector_type(4))) float f32x4;
typedef __attribute__((ext_vector_type(8))) _Float16 half8;

// Problem constants: B=8, N=M=2048, D=512, eps=0.1, max_iter=100, thresh=0.1
// d_out layout (floats): cost[8] | mu[16384] | nu[16384] | pi[33554432] | C[33554432]
// pi region doubles as G (=-C/eps, fp16) + GT (transpose) until the final kernel.

// ---------------- normalize + bf16 cast + output-head init ----------------
__global__ __launch_bounds__(256) void norm_cast_kernel(
    const float* __restrict__ x, const float* __restrict__ y,
    unsigned short* __restrict__ xnb, unsigned short* __restrict__ ynb,
    float* __restrict__ out)
{
    int tid = blockIdx.x * 256 + threadIdx.x;
    if (tid < 8) out[tid] = 0.0f;                       // cost accumulators
    if (tid < 16384) {
        out[8 + tid]     = 1.0f / 2048.0f;              // mu
        out[16392 + tid] = 1.0f / 2048.0f;              // nu
    }

    int w = tid >> 6;                                   // one wave per row, 32768 rows
    int lane = threadIdx.x & 63;
    const float* src = ((w < 16384) ? x : y) + (size_t)(w & 16383) * 512;
    unsigned short* dst = ((w < 16384) ? xnb : ynb) + (size_t)(w & 16383) * 512;

    float4 a = ((const float4*)src)[lane * 2];
    float4 b = ((const float4*)src)[lane * 2 + 1];
    float ss = a.x*a.x + a.y*a.y + a.z*a.z + a.w*a.w
             + b.x*b.x + b.y*b.y + b.z*b.z + b.w*b.w;
#pragma unroll
    for (int off = 32; off > 0; off >>= 1) ss += __shfl_xor(ss, off);
    float rn = rsqrtf(ss);

    float v[8] = {a.x*rn, a.y*rn, a.z*rn, a.w*rn, b.x*rn, b.y*rn, b.z*rn, b.w*rn};
    unsigned short o[8];
#pragma unroll
    for (int i = 0; i < 8; ++i) {
        unsigned int u = __float_as_uint(v[i]);
        o[i] = (unsigned short)((u + 0x7fffu + ((u >> 16) & 1u)) >> 16);  // RNE to bf16
    }
    unsigned int w0 = (unsigned)o[0] | ((unsigned)o[1] << 16);
    unsigned int w1 = (unsigned)o[2] | ((unsigned)o[3] << 16);
    unsigned int w2 = (unsigned)o[4] | ((unsigned)o[5] << 16);
    unsigned int w3 = (unsigned)o[6] | ((unsigned)o[7] << 16);
    uint4 pk; pk.x = w0; pk.y = w1; pk.z = w2; pk.w = w3;
    *(uint4*)(dst + lane * 8) = pk;
}

// ---------------- batched bf16 MFMA GEMM: C = 1 - xn·ynT, writes C fp32 + G fp16 ----
__global__ __launch_bounds__(256) void gemm_kernel(
    const unsigned short* __restrict__ xnb, const unsigned short* __restrict__ ynb,
    float* __restrict__ Cout, _Float16* __restrict__ G)
{
    __shared__ __align__(16) unsigned short As[128 * 64];
    __shared__ __align__(16) unsigned short Bs[128 * 64];

    int bid = blockIdx.x;
    int b  = bid >> 8;                 // 256 tiles per batch
    int t  = bid & 255;
    int tn = t >> 4, tm = t & 15;      // 128x128 tile coords
    const unsigned short* Abase = xnb + ((size_t)b * 2048 + tn * 128) * 512;
    const unsigned short* Bbase = ynb + ((size_t)b * 2048 + tm * 128) * 512;

    int tid = threadIdx.x;
    int wave = tid >> 6, lane = tid & 63;
    int wr = wave >> 1, wc = wave & 1;
    int quad = lane >> 4, l16 = lane & 15;

    f32x4 acc[4][4] = {};

    for (int k0 = 0; k0 < 512; k0 += 64) {
        // stage 128x64 bf16 tiles; XOR-swizzled granules -> conflict-free ds_read_b128
#pragma unroll
        for (int rr = 0; rr < 4; ++rr) {
            int chunk = rr * 256 + tid;         // 0..1023
            int row = chunk >> 3;               // 0..127
            int gr  = chunk & 7;                // 8-elem granule
            int sgr = gr ^ (row & 7);
            *(uint4*)(As + row * 64 + sgr * 8) =
                *(const uint4*)(Abase + (size_t)row * 512 + k0 + gr * 8);
            *(uint4*)(Bs + row * 64 + sgr * 8) =
                *(const uint4*)(Bbase + (size_t)row * 512 + k0 + gr * 8);
        }
        __syncthreads();
#pragma unroll
        for (int kk = 0; kk < 64; kk += 32) {
            bf16x8 af[4], bfr[4];
            int g = (kk >> 3) + quad;
#pragma unroll
            for (int i = 0; i < 4; ++i) {
                int rowA = wr * 64 + i * 16 + l16;
                af[i] = *(const bf16x8*)(As + rowA * 64 + ((g ^ (rowA & 7)) << 3));
                int rowB = wc * 64 + i * 16 + l16;
                bfr[i] = *(const bf16x8*)(Bs + rowB * 64 + ((g ^ (rowB & 7)) << 3));
            }
#pragma unroll
            for (int i = 0; i < 4; ++i)
#pragma unroll
                for (int j = 0; j < 4; ++j)
                    acc[i][j] = __builtin_amdgcn_mfma_f32_16x16x32_bf16(
                        af[i], bfr[j], acc[i][j], 0, 0, 0);
        }
        __syncthreads();
    }

    // epilogue: C/D layout col=lane&15, row=quad*4+reg
    size_t cbase = (size_t)b * 2048 * 2048;
#pragma unroll
    for (int i = 0; i < 4; ++i) {
#pragma unroll
        for (int j = 0; j < 4; ++j) {
            int n0 = tn * 128 + wr * 64 + i * 16 + quad * 4;
            int m  = tm * 128 + wc * 64 + j * 16 + l16;
#pragma unroll
            for (int rg = 0; rg < 4; ++rg) {
                float c = 1.0f - acc[i][j][rg];
                size_t idx = cbase + (size_t)(n0 + rg) * 2048 + m;
                Cout[idx] = c;
                G[idx] = (_Float16)(-10.0f * c);   // -C/eps
            }
        }
    }
}

// ---------------- fp16 transpose (per batch 2048x2048), 64x64 tiles ----------------
__global__ __launch_bounds__(256) void transpose_kernel(
    const unsigned short* __restrict__ G, unsigned short* __restrict__ GT)
{
    __shared__ __align__(16) unsigned short tile[64][68];
    int bid = blockIdx.x;
    int b  = bid >> 10;
    int t2 = bid & 1023;
    int tr = t2 >> 5, tc = t2 & 31;
    int t  = threadIdx.x;
    int cr = t >> 4;
    int cc = (t & 15) * 4;

    const unsigned short* src = G + ((size_t)b * 2048 + tr * 64) * 2048 + tc * 64;
#pragma unroll
    for (int rr = 0; rr < 4; ++rr) {
        int row = cr * 4 + rr;
        *(uint2*)&tile[row][cc] = *(const uint2*)(src + (size_t)row * 2048 + cc);
    }
    __syncthreads();
    unsigned short* dst = GT + ((size_t)b * 2048 + tc * 64) * 2048 + tr * 64;
#pragma unroll
    for (int rr = 0; rr < 4; ++rr) {
        int row = cr * 4 + rr;
        unsigned int w0 = (unsigned)tile[cc + 0][row] | ((unsigned)tile[cc + 1][row] << 16);
        unsigned int w1 = (unsigned)tile[cc + 2][row] | ((unsigned)tile[cc + 3][row] << 16);
        uint2 pk; pk.x = w0; pk.y = w1;
        *(uint2*)(dst + (size_t)row * 2048 + cc) = pk;
    }
}

// ---------------- cooperative Sinkhorn loop ----------------
__device__ __forceinline__ float row_lse_2048(const _Float16* __restrict__ row,
                                              const float* __restrict__ vec, int lane)
{
    float vals[32];
    float mx = -3.0e38f;
#pragma unroll
    for (int c = 0; c < 4; ++c) {
        int m0 = c * 512 + lane * 8;
        half8 h  = *(const half8*)(row + m0);
        float4 f0 = *(const float4*)(vec + m0);
        float4 f1 = *(const float4*)(vec + m0 + 4);
        float tv[8] = { f0.x + (float)h[0], f0.y + (float)h[1],
                        f0.z + (float)h[2], f0.w + (float)h[3],
                        f1.x + (float)h[4], f1.y + (float)h[5],
                        f1.z + (float)h[6], f1.w + (float)h[7] };
#pragma unroll
        for (int j = 0; j < 8; ++j) { vals[c * 8 + j] = tv[j]; mx = fmaxf(mx, tv[j]); }
    }
#pragma unroll
    for (int off = 32; off > 0; off >>= 1) mx = fmaxf(mx, __shfl_xor(mx, off));
    float s = 0.0f;
#pragma unroll
    for (int i = 0; i < 32; ++i) s += __expf(vals[i] - mx);
#pragma unroll
    for (int off = 32; off > 0; off >>= 1) s += __shfl_xor(s, off);
    return mx + __logf(s);
}

// __launch_bounds__(256,4): 4 waves/EU => 4 blocks/CU (128-VGPR cap; kernel
// uses ~100 VGPRs so no spill expected). Grid is sized at launch from a
// runtime occupancy query so the cooperative launch can NEVER exceed
// residency (the earlier blind 1024-block launch under (256,2) was rejected
// by the runtime and silently no-opped). Target: 1024 blocks = 16 waves/CU,
// doubling latency-hiding for the load->cvt->fmax->exp dependent chain.
__global__ __launch_bounds__(256, 4) void sinkhorn_kernel(
    const _Float16* __restrict__ G, const _Float16* __restrict__ GT,
    float* __restrict__ us, float* __restrict__ vs, float* __restrict__ errb)
{
    cg::grid_group grid = cg::this_grid();
    int tid = blockIdx.x * 256 + threadIdx.x;
    if (tid < 16384) { us[tid] = 0.0f; vs[tid] = 0.0f; }
    if (tid < 128) errb[tid] = 0.0f;
    grid.sync();

    const float log_mu = logf(1.0f / 2048.0f + 1e-8f);   // == log_nu
    int gwave = tid >> 6;
    int lane  = threadIdx.x & 63;
    const int nwaves = (gridDim.x * 256) >> 6;

    for (int it = 0; it < 100; ++it) {
        // u-pass: rows of G   (us/vs store the eps-scaled duals u/eps, v/eps)
        float werr = 0.0f;
        for (int r = gwave; r < 16384; r += nwaves) {
            int b = r >> 11;
            float lse = row_lse_2048(G + (size_t)r * 2048, vs + (b << 11), lane);
            float un = log_mu - lse;
            werr += fabsf(un - us[r]);
            if (lane == 0) us[r] = un;
        }
        if (lane == 0) atomicAdd(&errb[it], werr * 0.1f);  // eps*sum|d(us)| = sum|du|
        grid.sync();
        // v-pass: rows of GT (columns of G), uses updated u
        for (int r = gwave; r < 16384; r += nwaves) {
            int b = r >> 11;
            float lse = row_lse_2048(GT + (size_t)r * 2048, us + (b << 11), lane);
            if (lane == 0) vs[r] = log_mu - lse;
        }
        float err = errb[it] * 0.125f;                     // mean over B=8
        grid.sync();
        if (err < 0.1f) break;  // uniform across grid: same errb value everywhere
    }
}

// ---------------- pi = exp(us + vs - C/eps), cost = sum(pi*C) ----------------
__global__ __launch_bounds__(256) void pi_cost_kernel(
    const float* __restrict__ C, const float* __restrict__ us, const float* __restrict__ vs,
    float* __restrict__ pi, float* __restrict__ cost)
{
    __shared__ float red[4];
    int r = blockIdx.x;               // 16384 rows
    int b = r >> 11;
    const float* Crow = C + (size_t)r * 2048;
    float* Prow = pi + (size_t)r * 2048;
    float u = us[r];
    const float* vb = vs + (b << 11);
    int t = threadIdx.x;
    float csum = 0.0f;
#pragma unroll
    for (int cch = 0; cch < 2; ++cch) {
        int m0 = (cch * 256 + t) * 4;
        float4 cv = *(const float4*)(Crow + m0);
        float4 vv = *(const float4*)(vb + m0);
        float4 p;
        p.x = __expf(u + vv.x - 10.0f * cv.x);
        p.y = __expf(u + vv.y - 10.0f * cv.y);
        p.z = __expf(u + vv.z - 10.0f * cv.z);
        p.w = __expf(u + vv.w - 10.0f * cv.w);
        *(float4*)(Prow + m0) = p;
        csum += p.x * cv.x + p.y * cv.y + p.z * cv.z + p.w * cv.w;
    }
#pragma unroll
    for (int off = 32; off > 0; off >>= 1) csum += __shfl_xor(csum, off);
    int wave = t >> 6, lane = t & 63;
    if (lane == 0) red[wave] = csum;
    __syncthreads();
    if (t == 0) atomicAdd(&cost[b], red[0] + red[1] + red[2] + red[3]);
}

extern "C" void kernel_launch(void* const* d_in, const int* in_sizes, int n_in,
                              void* d_out, int out_size, void* d_ws, size_t ws_size,
                              hipStream_t stream) {
    const float* x = (const float*)d_in[0];
    const float* y = (const float*)d_in[1];
    float* out = (float*)d_out;

    char* w = (char*)d_ws;
    unsigned short* xnb = (unsigned short*)w;                        // 16 MB
    unsigned short* ynb = (unsigned short*)(w + 16777216);           // 16 MB
    float* us   = (float*)(w + 2 * 16777216);                        // 64 KB
    float* vs   = (float*)(w + 2 * 16777216 + 65536);                // 64 KB
    float* errb = (float*)(w + 2 * 16777216 + 2 * 65536);            // 512 B

    float* cost = out;                    // 8
    float* pi   = out + 32776;            // 33554432
    float* Cout = out + 33587208;         // 33554432
    // G/GT live in the pi region until the final kernel overwrites it
    unsigned short* Gh  = (unsigned short*)pi;
    unsigned short* GTh = Gh + 33554432;

    // Size the cooperative grid from actual occupancy (host query, capture-safe,
    // computed once). Never exceeds residency -> launch cannot no-op.
    static int coopGrid = 0;
    if (coopGrid == 0) {
        int nb = 0;
        hipError_t e = hipOccupancyMaxActiveBlocksPerMultiprocessor(
            &nb, (const void*)sinkhorn_kernel, 256, 0);
        if (e != hipSuccess || nb < 1) nb = 2;   // conservative fallback (known-good 512)
        int cus = 256;
        hipDeviceProp_t prop;
        if (hipGetDeviceProperties(&prop, 0) == hipSuccess && prop.multiProcessorCount > 0)
            cus = prop.multiProcessorCount;
        long g = (long)nb * cus;
        if (g > 1024) g = 1024;                  // 4 blocks/CU target cap
        if (g < 64)   g = 64;                    // init coverage needs >=16384 threads
        coopGrid = (int)g;
    }

    norm_cast_kernel<<<8192, 256, 0, stream>>>(x, y, xnb, ynb, out);
    gemm_kernel<<<2048, 256, 0, stream>>>(xnb, ynb, Cout, (_Float16*)Gh);
    transpose_kernel<<<8192, 256, 0, stream>>>(Gh, GTh);

    const _Float16* Gc  = (const _Float16*)Gh;
    const _Float16* GTc = (const _Float16*)GTh;
    void* cargs[] = { (void*)&Gc, (void*)&GTc, (void*)&us, (void*)&vs, (void*)&errb };
    hipLaunchCooperativeKernel((void*)sinkhorn_kernel, dim3(coopGrid), dim3(256),
                               cargs, 0, stream);

    pi_cost_kernel<<<16384, 256, 0, stream>>>(Cout, us, vs, pi, cost);
}

// Round 2
// 945.123 us; speedup vs baseline: 1.1154x; 1.1154x over previous
//
#include <hip/hip_runtime.h>
#include <hip/hip_fp16.h>
#include <hip/hip_cooperative_groups.h>

namespace cg = cooperative_groups;

typedef __attribute__((ext_vector_type(8))) short bf16x8;
typedef __attribute__((ext_vector_type(4))) float f32x4;
typedef __attribute__((ext_vector_type(8))) _Float16 half8;
typedef __attribute__((ext_vector_type(4))) _Float16 half4;

// Problem constants: B=8, N=M=2048, D=512, eps=0.1, max_iter=100, thresh=0.1
// d_out layout (floats): cost[8] | mu[16384] | nu[16384] | pi[33554432] | C[33554432]
// pi region doubles as G (=-C/eps, fp16) + GT (transpose) until the final kernel.

// ---------------- normalize + bf16 cast + output-head init ----------------
__global__ __launch_bounds__(256) void norm_cast_kernel(
    const float* __restrict__ x, const float* __restrict__ y,
    unsigned short* __restrict__ xnb, unsigned short* __restrict__ ynb,
    float* __restrict__ out)
{
    int tid = blockIdx.x * 256 + threadIdx.x;
    if (tid < 8) out[tid] = 0.0f;                       // cost accumulators
    if (tid < 16384) {
        out[8 + tid]     = 1.0f / 2048.0f;              // mu
        out[16392 + tid] = 1.0f / 2048.0f;              // nu
    }

    int w = tid >> 6;                                   // one wave per row, 32768 rows
    int lane = threadIdx.x & 63;
    const float* src = ((w < 16384) ? x : y) + (size_t)(w & 16383) * 512;
    unsigned short* dst = ((w < 16384) ? xnb : ynb) + (size_t)(w & 16383) * 512;

    float4 a = ((const float4*)src)[lane * 2];
    float4 b = ((const float4*)src)[lane * 2 + 1];
    float ss = a.x*a.x + a.y*a.y + a.z*a.z + a.w*a.w
             + b.x*b.x + b.y*b.y + b.z*b.z + b.w*b.w;
#pragma unroll
    for (int off = 32; off > 0; off >>= 1) ss += __shfl_xor(ss, off);
    float rn = rsqrtf(ss);

    float v[8] = {a.x*rn, a.y*rn, a.z*rn, a.w*rn, b.x*rn, b.y*rn, b.z*rn, b.w*rn};
    unsigned short o[8];
#pragma unroll
    for (int i = 0; i < 8; ++i) {
        unsigned int u = __float_as_uint(v[i]);
        o[i] = (unsigned short)((u + 0x7fffu + ((u >> 16) & 1u)) >> 16);  // RNE to bf16
    }
    unsigned int w0 = (unsigned)o[0] | ((unsigned)o[1] << 16);
    unsigned int w1 = (unsigned)o[2] | ((unsigned)o[3] << 16);
    unsigned int w2 = (unsigned)o[4] | ((unsigned)o[5] << 16);
    unsigned int w3 = (unsigned)o[6] | ((unsigned)o[7] << 16);
    uint4 pk; pk.x = w0; pk.y = w1; pk.z = w2; pk.w = w3;
    *(uint4*)(dst + lane * 8) = pk;
}

// ---------------- batched bf16 MFMA GEMM: C = 1 - xn·ynT ----------------
// Writes C fp32, G fp16 (row-major) AND GT fp16 (transposed) directly.
// GT goes through a padded LDS bounce (staging LDS is dead by the epilogue)
// so the global GT writes stay fully coalesced; this removes the standalone
// transpose kernel (64 MB read + 64 MB write + one dispatch).
__global__ __launch_bounds__(256) void gemm_kernel(
    const unsigned short* __restrict__ xnb, const unsigned short* __restrict__ ynb,
    float* __restrict__ Cout, _Float16* __restrict__ G, _Float16* __restrict__ GT)
{
    // staging (2 x 128x64 = 16384 shorts) and GT-bounce tile (128x136 = 17408
    // shorts, +8 pad keeps ds_read_b128 16B-aligned and spreads banks) share
    // one allocation.
    __shared__ __align__(16) unsigned short smem[128 * 136];
    unsigned short* As = smem;
    unsigned short* Bs = smem + 128 * 64;

    int bid = blockIdx.x;
    int b  = bid >> 8;                 // 256 tiles per batch
    int t  = bid & 255;
    int tn = t >> 4, tm = t & 15;      // 128x128 tile coords
    const unsigned short* Abase = xnb + ((size_t)b * 2048 + tn * 128) * 512;
    const unsigned short* Bbase = ynb + ((size_t)b * 2048 + tm * 128) * 512;

    int tid = threadIdx.x;
    int wave = tid >> 6, lane = tid & 63;
    int wr = wave >> 1, wc = wave & 1;
    int quad = lane >> 4, l16 = lane & 15;

    f32x4 acc[4][4] = {};

    for (int k0 = 0; k0 < 512; k0 += 64) {
        // stage 128x64 bf16 tiles; XOR-swizzled granules -> conflict-free ds_read_b128
#pragma unroll
        for (int rr = 0; rr < 4; ++rr) {
            int chunk = rr * 256 + tid;         // 0..1023
            int row = chunk >> 3;               // 0..127
            int gr  = chunk & 7;                // 8-elem granule
            int sgr = gr ^ (row & 7);
            *(uint4*)(As + row * 64 + sgr * 8) =
                *(const uint4*)(Abase + (size_t)row * 512 + k0 + gr * 8);
            *(uint4*)(Bs + row * 64 + sgr * 8) =
                *(const uint4*)(Bbase + (size_t)row * 512 + k0 + gr * 8);
        }
        __syncthreads();
#pragma unroll
        for (int kk = 0; kk < 64; kk += 32) {
            bf16x8 af[4], bfr[4];
            int g = (kk >> 3) + quad;
#pragma unroll
            for (int i = 0; i < 4; ++i) {
                int rowA = wr * 64 + i * 16 + l16;
                af[i] = *(const bf16x8*)(As + rowA * 64 + ((g ^ (rowA & 7)) << 3));
                int rowB = wc * 64 + i * 16 + l16;
                bfr[i] = *(const bf16x8*)(Bs + rowB * 64 + ((g ^ (rowB & 7)) << 3));
            }
#pragma unroll
            for (int i = 0; i < 4; ++i)
#pragma unroll
                for (int j = 0; j < 4; ++j)
                    acc[i][j] = __builtin_amdgcn_mfma_f32_16x16x32_bf16(
                        af[i], bfr[j], acc[i][j], 0, 0, 0);
        }
        __syncthreads();
    }

    // epilogue: C/D layout col=lane&15, row=quad*4+reg
    // C[n][m] / G[n][m] written direct (coalesced along m = l16);
    // GT tile stashed into LDS at [m_local][n_local], then written coalesced.
    unsigned short* gt = smem;             // reuse: staging is dead, synced above
    size_t cbase = (size_t)b * 2048 * 2048;
#pragma unroll
    for (int i = 0; i < 4; ++i) {
#pragma unroll
        for (int j = 0; j < 4; ++j) {
            int n0l = wr * 64 + i * 16 + quad * 4;   // local n base (multiple of 4)
            int ml  = wc * 64 + j * 16 + l16;        // local m
            int n0 = tn * 128 + n0l;
            int m  = tm * 128 + ml;
            half4 gv;
#pragma unroll
            for (int rg = 0; rg < 4; ++rg) {
                float c = 1.0f - acc[i][j][rg];
                size_t idx = cbase + (size_t)(n0 + rg) * 2048 + m;
                Cout[idx] = c;
                _Float16 gh = (_Float16)(-10.0f * c);   // -C/eps
                G[idx] = gh;
                gv[rg] = gh;
            }
            *(half4*)(gt + ml * 136 + n0l) = gv;     // 8B store, 8B-aligned
        }
    }
    __syncthreads();
    // write-out: 128 rows x 128 fp16 = 2048 uint4 chunks, 8 per thread
#pragma unroll
    for (int k = 0; k < 8; ++k) {
        int chunk = k * 256 + tid;
        int row = chunk >> 4;               // local m 0..127
        int c8  = chunk & 15;               // 8-elem column chunk
        uint4 vv = *(const uint4*)(gt + row * 136 + c8 * 8);
        *(uint4*)((unsigned short*)GT + cbase +
                  (size_t)(tm * 128 + row) * 2048 + tn * 128 + c8 * 8) = vv;
    }
}

// ---------------- cooperative Sinkhorn loop ----------------
__device__ __forceinline__ float row_lse_2048(const _Float16* __restrict__ row,
                                              const float* __restrict__ vec, int lane)
{
    float vals[32];
    float mx = -3.0e38f;
#pragma unroll
    for (int c = 0; c < 4; ++c) {
        int m0 = c * 512 + lane * 8;
        half8 h  = *(const half8*)(row + m0);
        float4 f0 = *(const float4*)(vec + m0);
        float4 f1 = *(const float4*)(vec + m0 + 4);
        float tv[8] = { f0.x + (float)h[0], f0.y + (float)h[1],
                        f0.z + (float)h[2], f0.w + (float)h[3],
                        f1.x + (float)h[4], f1.y + (float)h[5],
                        f1.z + (float)h[6], f1.w + (float)h[7] };
#pragma unroll
        for (int j = 0; j < 8; ++j) { vals[c * 8 + j] = tv[j]; mx = fmaxf(mx, tv[j]); }
    }
#pragma unroll
    for (int off = 32; off > 0; off >>= 1) mx = fmaxf(mx, __shfl_xor(mx, off));
    float s = 0.0f;
#pragma unroll
    for (int i = 0; i < 32; ++i) s += __expf(vals[i] - mx);
#pragma unroll
    for (int off = 32; off > 0; off >>= 1) s += __shfl_xor(s, off);
    return mx + __logf(s);
}

// R1 post-mortem: 1024-block coop grid REGRESSED sinkhorn 464->575 us.
// FETCH_SIZE=134MB/dispatch (= one cold pass; L3 serves all re-reads),
// VALUBusy 5%, HBM 3% -> per-iteration work sits at the L3/VALU floor and
// the marginal cost of grid.sync() scales with block count (2 syncs/iter).
// 512 blocks (2/CU) is the measured sweet spot; grid sized by occupancy
// query, capped at 512.
__global__ __launch_bounds__(256, 4) void sinkhorn_kernel(
    const _Float16* __restrict__ G, const _Float16* __restrict__ GT,
    float* __restrict__ us, float* __restrict__ vs, float* __restrict__ errb)
{
    cg::grid_group grid = cg::this_grid();
    int tid = blockIdx.x * 256 + threadIdx.x;
    if (tid < 16384) { us[tid] = 0.0f; vs[tid] = 0.0f; }
    if (tid < 128) errb[tid] = 0.0f;
    grid.sync();

    const float log_mu = logf(1.0f / 2048.0f + 1e-8f);   // == log_nu
    int gwave = tid >> 6;
    int lane  = threadIdx.x & 63;
    const int nwaves = (gridDim.x * 256) >> 6;

    for (int it = 0; it < 100; ++it) {
        // u-pass: rows of G   (us/vs store the eps-scaled duals u/eps, v/eps)
        float werr = 0.0f;
        for (int r = gwave; r < 16384; r += nwaves) {
            int b = r >> 11;
            float lse = row_lse_2048(G + (size_t)r * 2048, vs + (b << 11), lane);
            float un = log_mu - lse;
            werr += fabsf(un - us[r]);
            if (lane == 0) us[r] = un;
        }
        if (lane == 0) atomicAdd(&errb[it], werr * 0.1f);  // eps*sum|d(us)| = sum|du|
        grid.sync();
        // v-pass: rows of GT (columns of G), uses updated u
        for (int r = gwave; r < 16384; r += nwaves) {
            int b = r >> 11;
            float lse = row_lse_2048(GT + (size_t)r * 2048, us + (b << 11), lane);
            if (lane == 0) vs[r] = log_mu - lse;
        }
        float err = errb[it] * 0.125f;                     // mean over B=8
        grid.sync();
        if (err < 0.1f) break;  // uniform across grid: same errb value everywhere
    }
}

// ---------------- pi = exp(us + vs - C/eps), cost = sum(pi*C) ----------------
__global__ __launch_bounds__(256) void pi_cost_kernel(
    const float* __restrict__ C, const float* __restrict__ us, const float* __restrict__ vs,
    float* __restrict__ pi, float* __restrict__ cost)
{
    __shared__ float red[4];
    int r = blockIdx.x;               // 16384 rows
    int b = r >> 11;
    const float* Crow = C + (size_t)r * 2048;
    float* Prow = pi + (size_t)r * 2048;
    float u = us[r];
    const float* vb = vs + (b << 11);
    int t = threadIdx.x;
    float csum = 0.0f;
#pragma unroll
    for (int cch = 0; cch < 2; ++cch) {
        int m0 = (cch * 256 + t) * 4;
        float4 cv = *(const float4*)(Crow + m0);
        float4 vv = *(const float4*)(vb + m0);
        float4 p;
        p.x = __expf(u + vv.x - 10.0f * cv.x);
        p.y = __expf(u + vv.y - 10.0f * cv.y);
        p.z = __expf(u + vv.z - 10.0f * cv.z);
        p.w = __expf(u + vv.w - 10.0f * cv.w);
        *(float4*)(Prow + m0) = p;
        csum += p.x * cv.x + p.y * cv.y + p.z * cv.z + p.w * cv.w;
    }
#pragma unroll
    for (int off = 32; off > 0; off >>= 1) csum += __shfl_xor(csum, off);
    int wave = t >> 6, lane = t & 63;
    if (lane == 0) red[wave] = csum;
    __syncthreads();
    if (t == 0) atomicAdd(&cost[b], red[0] + red[1] + red[2] + red[3]);
}

extern "C" void kernel_launch(void* const* d_in, const int* in_sizes, int n_in,
                              void* d_out, int out_size, void* d_ws, size_t ws_size,
                              hipStream_t stream) {
    const float* x = (const float*)d_in[0];
    const float* y = (const float*)d_in[1];
    float* out = (float*)d_out;

    char* w = (char*)d_ws;
    unsigned short* xnb = (unsigned short*)w;                        // 16 MB
    unsigned short* ynb = (unsigned short*)(w + 16777216);           // 16 MB
    float* us   = (float*)(w + 2 * 16777216);                        // 64 KB
    float* vs   = (float*)(w + 2 * 16777216 + 65536);                // 64 KB
    float* errb = (float*)(w + 2 * 16777216 + 2 * 65536);            // 512 B

    float* cost = out;                    // 8
    float* pi   = out + 32776;            // 33554432
    float* Cout = out + 33587208;         // 33554432
    // G/GT live in the pi region until the final kernel overwrites it
    unsigned short* Gh  = (unsigned short*)pi;
    unsigned short* GTh = Gh + 33554432;

    // Cooperative grid from occupancy query, capped at the measured-best 512
    // blocks (2/CU). Query keeps the launch residency-safe on any config.
    static int coopGrid = 0;
    if (coopGrid == 0) {
        int nb = 0;
        hipError_t e = hipOccupancyMaxActiveBlocksPerMultiprocessor(
            &nb, (const void*)sinkhorn_kernel, 256, 0);
        if (e != hipSuccess || nb < 1) nb = 2;
        int cus = 256;
        hipDeviceProp_t prop;
        if (hipGetDeviceProperties(&prop, 0) == hipSuccess && prop.multiProcessorCount > 0)
            cus = prop.multiProcessorCount;
        long g = (long)nb * cus;
        if (g > 512) g = 512;                    // measured sweet spot (R1)
        if (g < 64)  g = 64;                     // init coverage needs >=16384 threads
        coopGrid = (int)g;
    }

    norm_cast_kernel<<<8192, 256, 0, stream>>>(x, y, xnb, ynb, out);
    gemm_kernel<<<2048, 256, 0, stream>>>(xnb, ynb, Cout, (_Float16*)Gh, (_Float16*)GTh);

    const _Float16* Gc  = (const _Float16*)Gh;
    const _Float16* GTc = (const _Float16*)GTh;
    void* cargs[] = { (void*)&Gc, (void*)&GTc, (void*)&us, (void*)&vs, (void*)&errb };
    hipLaunchCooperativeKernel((void*)sinkhorn_kernel, dim3(coopGrid), dim3(256),
                               cargs, 0, stream);

    pi_cost_kernel<<<16384, 256, 0, stream>>>(Cout, us, vs, pi, cost);
}

// Round 4
// 753.529 us; speedup vs baseline: 1.3990x; 1.2543x over previous
//
#include <hip/hip_runtime.h>
#include <hip/hip_fp16.h>
#include <hip/hip_cooperative_groups.h>

typedef __attribute__((ext_vector_type(8))) short bf16x8;
typedef __attribute__((ext_vector_type(4))) float f32x4;
typedef __attribute__((ext_vector_type(8))) _Float16 half8;
typedef __attribute__((ext_vector_type(4))) _Float16 half4;

// Problem constants: B=8, N=M=2048, D=512, eps=0.1, max_iter=100, thresh=0.1
// d_out layout (floats): cost[8] | mu[16384] | nu[16384] | pi[33554432] | C[33554432]
// pi region doubles as G (=-C/eps, fp16) + GT (transpose) until the final kernel.

// ---------------- normalize + bf16 cast + state init ----------------
__global__ __launch_bounds__(256) void norm_cast_kernel(
    const float* __restrict__ x, const float* __restrict__ y,
    unsigned short* __restrict__ xnb, unsigned short* __restrict__ ynb,
    float* __restrict__ out, float* __restrict__ us, float* __restrict__ vs,
    float* __restrict__ errb, int* __restrict__ bar)
{
    int tid = blockIdx.x * 256 + threadIdx.x;
    if (tid < 8) out[tid] = 0.0f;                       // cost accumulators
    if (tid < 16384) {
        out[8 + tid]     = 1.0f / 2048.0f;              // mu
        out[16392 + tid] = 1.0f / 2048.0f;              // nu
        us[tid] = 0.0f;                                 // sinkhorn state init here:
        vs[tid] = 0.0f;                                 // saves the bootstrap grid.sync
    }
    if (tid < 128) errb[tid] = 0.0f;
    if (tid < 64)  bar[tid]  = 0;                       // barrier cnt/gen

    int w = tid >> 6;                                   // one wave per row, 32768 rows
    int lane = threadIdx.x & 63;
    const float* src = ((w < 16384) ? x : y) + (size_t)(w & 16383) * 512;
    unsigned short* dst = ((w < 16384) ? xnb : ynb) + (size_t)(w & 16383) * 512;

    float4 a = ((const float4*)src)[lane * 2];
    float4 b = ((const float4*)src)[lane * 2 + 1];
    float ss = a.x*a.x + a.y*a.y + a.z*a.z + a.w*a.w
             + b.x*b.x + b.y*b.y + b.z*b.z + b.w*b.w;
#pragma unroll
    for (int off = 32; off > 0; off >>= 1) ss += __shfl_xor(ss, off);
    float rn = rsqrtf(ss);

    float v[8] = {a.x*rn, a.y*rn, a.z*rn, a.w*rn, b.x*rn, b.y*rn, b.z*rn, b.w*rn};
    unsigned short o[8];
#pragma unroll
    for (int i = 0; i < 8; ++i) {
        unsigned int u = __float_as_uint(v[i]);
        o[i] = (unsigned short)((u + 0x7fffu + ((u >> 16) & 1u)) >> 16);  // RNE to bf16
    }
    unsigned int w0 = (unsigned)o[0] | ((unsigned)o[1] << 16);
    unsigned int w1 = (unsigned)o[2] | ((unsigned)o[3] << 16);
    unsigned int w2 = (unsigned)o[4] | ((unsigned)o[5] << 16);
    unsigned int w3 = (unsigned)o[6] | ((unsigned)o[7] << 16);
    uint4 pk; pk.x = w0; pk.y = w1; pk.z = w2; pk.w = w3;
    *(uint4*)(dst + lane * 8) = pk;
}

// ---------------- batched bf16 MFMA GEMM: C = 1 - xn·ynT ----------------
// Writes C fp32, G fp16 (row-major) AND GT fp16 (transposed, via LDS bounce).
__global__ __launch_bounds__(256) void gemm_kernel(
    const unsigned short* __restrict__ xnb, const unsigned short* __restrict__ ynb,
    float* __restrict__ Cout, _Float16* __restrict__ G, _Float16* __restrict__ GT)
{
    __shared__ __align__(16) unsigned short smem[128 * 136];
    unsigned short* As = smem;
    unsigned short* Bs = smem + 128 * 64;

    int bid = blockIdx.x;
    int b  = bid >> 8;                 // 256 tiles per batch
    int t  = bid & 255;
    int tn = t >> 4, tm = t & 15;      // 128x128 tile coords
    const unsigned short* Abase = xnb + ((size_t)b * 2048 + tn * 128) * 512;
    const unsigned short* Bbase = ynb + ((size_t)b * 2048 + tm * 128) * 512;

    int tid = threadIdx.x;
    int wave = tid >> 6, lane = tid & 63;
    int wr = wave >> 1, wc = wave & 1;
    int quad = lane >> 4, l16 = lane & 15;

    f32x4 acc[4][4] = {};

    for (int k0 = 0; k0 < 512; k0 += 64) {
#pragma unroll
        for (int rr = 0; rr < 4; ++rr) {
            int chunk = rr * 256 + tid;         // 0..1023
            int row = chunk >> 3;               // 0..127
            int gr  = chunk & 7;                // 8-elem granule
            int sgr = gr ^ (row & 7);
            *(uint4*)(As + row * 64 + sgr * 8) =
                *(const uint4*)(Abase + (size_t)row * 512 + k0 + gr * 8);
            *(uint4*)(Bs + row * 64 + sgr * 8) =
                *(const uint4*)(Bbase + (size_t)row * 512 + k0 + gr * 8);
        }
        __syncthreads();
#pragma unroll
        for (int kk = 0; kk < 64; kk += 32) {
            bf16x8 af[4], bfr[4];
            int g = (kk >> 3) + quad;
#pragma unroll
            for (int i = 0; i < 4; ++i) {
                int rowA = wr * 64 + i * 16 + l16;
                af[i] = *(const bf16x8*)(As + rowA * 64 + ((g ^ (rowA & 7)) << 3));
                int rowB = wc * 64 + i * 16 + l16;
                bfr[i] = *(const bf16x8*)(Bs + rowB * 64 + ((g ^ (rowB & 7)) << 3));
            }
#pragma unroll
            for (int i = 0; i < 4; ++i)
#pragma unroll
                for (int j = 0; j < 4; ++j)
                    acc[i][j] = __builtin_amdgcn_mfma_f32_16x16x32_bf16(
                        af[i], bfr[j], acc[i][j], 0, 0, 0);
        }
        __syncthreads();
    }

    // epilogue: C/D layout col=lane&15, row=quad*4+reg
    unsigned short* gt = smem;             // reuse: staging dead, synced above
    size_t cbase = (size_t)b * 2048 * 2048;
#pragma unroll
    for (int i = 0; i < 4; ++i) {
#pragma unroll
        for (int j = 0; j < 4; ++j) {
            int n0l = wr * 64 + i * 16 + quad * 4;   // local n base (multiple of 4)
            int ml  = wc * 64 + j * 16 + l16;        // local m
            int n0 = tn * 128 + n0l;
            int m  = tm * 128 + ml;
            half4 gv;
#pragma unroll
            for (int rg = 0; rg < 4; ++rg) {
                float c = 1.0f - acc[i][j][rg];
                size_t idx = cbase + (size_t)(n0 + rg) * 2048 + m;
                Cout[idx] = c;
                _Float16 gh = (_Float16)(-10.0f * c);   // -C/eps
                G[idx] = gh;
                gv[rg] = gh;
            }
            *(half4*)(gt + ml * 136 + n0l) = gv;     // 8B store, 8B-aligned
        }
    }
    __syncthreads();
#pragma unroll
    for (int k = 0; k < 8; ++k) {
        int chunk = k * 256 + tid;
        int row = chunk >> 4;               // local m 0..127
        int c8  = chunk & 15;               // 8-elem column chunk
        uint4 vv = *(const uint4*)(gt + row * 136 + c8 * 8);
        *(uint4*)((unsigned short*)GT + cbase +
                  (size_t)(tm * 128 + row) * 2048 + tn * 128 + c8 * 8) = vv;
    }
}

// ---------------- cooperative Sinkhorn loop ----------------
__device__ __forceinline__ float row_lse_2048(const _Float16* __restrict__ row,
                                              const float* __restrict__ vec, int lane)
{
    float vals[32];
    float mx = -3.0e38f;
#pragma unroll
    for (int c = 0; c < 4; ++c) {
        int m0 = c * 512 + lane * 8;
        half8 h  = *(const half8*)(row + m0);
        float4 f0 = *(const float4*)(vec + m0);
        float4 f1 = *(const float4*)(vec + m0 + 4);
        float tv[8] = { f0.x + (float)h[0], f0.y + (float)h[1],
                        f0.z + (float)h[2], f0.w + (float)h[3],
                        f1.x + (float)h[4], f1.y + (float)h[5],
                        f1.z + (float)h[6], f1.w + (float)h[7] };
#pragma unroll
        for (int j = 0; j < 8; ++j) { vals[c * 8 + j] = tv[j]; mx = fmaxf(mx, tv[j]); }
    }
#pragma unroll
    for (int off = 32; off > 0; off >>= 1) mx = fmaxf(mx, __shfl_xor(mx, off));
    float s = 0.0f;
#pragma unroll
    for (int i = 0; i < 32; ++i) s += __expf(vals[i] - mx);
#pragma unroll
    for (int off = 32; off > 0; off >>= 1) s += __shfl_xor(s, off);
    return mx + __logf(s);
}

// Lean grid barrier (sense via generation counter). R1/R2 showed cg::sync
// dominates sinkhorn (1024->512 blocks saved 227us with identical work):
// arrive = device-scope ACQ_REL fetch_add on cnt; last block resets cnt
// (relaxed, released-before gen bump) and RELEASE-bumps gen; spinners poll
// gen RELAXED then ACQUIRE-load once. cnt reset happens-before gen bump, so
// barrier k+1 arrivals (only possible after observing gen k+1) see cnt=0;
// spinners never touch cnt -> no corruption window. gen monotone in-run,
// re-zeroed by norm_cast each graph replay.
__device__ __forceinline__ void gridbar(int* cnt, int* gen, int nb)
{
    __syncthreads();
    if (threadIdx.x == 0) {
        int g = __hip_atomic_load(gen, __ATOMIC_RELAXED, __HIP_MEMORY_SCOPE_AGENT);
        int v = __hip_atomic_fetch_add(cnt, 1, __ATOMIC_ACQ_REL, __HIP_MEMORY_SCOPE_AGENT);
        if (v == nb - 1) {
            __hip_atomic_store(cnt, 0, __ATOMIC_RELAXED, __HIP_MEMORY_SCOPE_AGENT);
            __hip_atomic_fetch_add(gen, 1, __ATOMIC_RELEASE, __HIP_MEMORY_SCOPE_AGENT);
        } else {
            while (__hip_atomic_load(gen, __ATOMIC_RELAXED, __HIP_MEMORY_SCOPE_AGENT) == g)
                __builtin_amdgcn_s_sleep(1);
            (void)__hip_atomic_load(gen, __ATOMIC_ACQUIRE, __HIP_MEMORY_SCOPE_AGENT);
        }
    }
    __syncthreads();
}

__global__ __launch_bounds__(256, 4) void sinkhorn_kernel(
    const _Float16* __restrict__ G, const _Float16* __restrict__ GT,
    float* __restrict__ us, float* __restrict__ vs, float* __restrict__ errb,
    int* __restrict__ bar)
{
    __shared__ float wred[4];
    int tid = blockIdx.x * 256 + threadIdx.x;
    const float log_mu = logf(1.0f / 2048.0f + 1e-8f);   // == log_nu
    int gwave = tid >> 6;
    int wave  = threadIdx.x >> 6;
    int lane  = threadIdx.x & 63;
    const int nwaves = (gridDim.x * 256) >> 6;           // 512 blocks -> 8 rows/wave
    const int nb = (int)gridDim.x;
    int* cnt = bar;
    int* gen = bar + 32;                                 // separate cacheline

    for (int it = 0; it < 100; ++it) {
        // u-pass: rows of G   (us/vs store the eps-scaled duals u/eps, v/eps)
        float werr = 0.0f;
        for (int r = gwave; r < 16384; r += nwaves) {
            int b = r >> 11;
            float lse = row_lse_2048(G + (size_t)r * 2048, vs + (b << 11), lane);
            float un = log_mu - lse;
            werr += fabsf(un - us[r]);
            if (lane == 0) us[r] = un;
        }
        // block-local reduce -> one atomicAdd per block (4x less contention)
        if (lane == 0) wred[wave] = werr;
        __syncthreads();
        if (threadIdx.x == 0)
            atomicAdd(&errb[it], (wred[0] + wred[1] + wred[2] + wred[3]) * 0.1f);
        gridbar(cnt, gen, nb);
        float err = errb[it] * 0.125f;                   // mean over B=8
        // v-pass: rows of GT (columns of G), uses updated u
        for (int r = gwave; r < 16384; r += nwaves) {
            int b = r >> 11;
            float lse = row_lse_2048(GT + (size_t)r * 2048, us + (b << 11), lane);
            if (lane == 0) vs[r] = log_mu - lse;
        }
        gridbar(cnt, gen, nb);
        if (err < 0.1f) break;  // uniform across grid: same errb value everywhere
    }
}

// ---------------- pi = exp(us + vs - C/eps), cost = sum(pi*C) ----------------
__global__ __launch_bounds__(256) void pi_cost_kernel(
    const float* __restrict__ C, const float* __restrict__ us, const float* __restrict__ vs,
    float* __restrict__ pi, float* __restrict__ cost)
{
    __shared__ float red[4];
    int r = blockIdx.x;               // 16384 rows
    int b = r >> 11;
    const float* Crow = C + (size_t)r * 2048;
    float* Prow = pi + (size_t)r * 2048;
    float u = us[r];
    const float* vb = vs + (b << 11);
    int t = threadIdx.x;
    float csum = 0.0f;
#pragma unroll
    for (int cch = 0; cch < 2; ++cch) {
        int m0 = (cch * 256 + t) * 4;
        float4 cv = *(const float4*)(Crow + m0);
        float4 vv = *(const float4*)(vb + m0);
        float4 p;
        p.x = __expf(u + vv.x - 10.0f * cv.x);
        p.y = __expf(u + vv.y - 10.0f * cv.y);
        p.z = __expf(u + vv.z - 10.0f * cv.z);
        p.w = __expf(u + vv.w - 10.0f * cv.w);
        *(float4*)(Prow + m0) = p;
        csum += p.x * cv.x + p.y * cv.y + p.z * cv.z + p.w * cv.w;
    }
#pragma unroll
    for (int off = 32; off > 0; off >>= 1) csum += __shfl_xor(csum, off);
    int wave = t >> 6, lane = t & 63;
    if (lane == 0) red[wave] = csum;
    __syncthreads();
    if (t == 0) atomicAdd(&cost[b], red[0] + red[1] + red[2] + red[3]);
}

extern "C" void kernel_launch(void* const* d_in, const int* in_sizes, int n_in,
                              void* d_out, int out_size, void* d_ws, size_t ws_size,
                              hipStream_t stream) {
    const float* x = (const float*)d_in[0];
    const float* y = (const float*)d_in[1];
    float* out = (float*)d_out;

    char* w = (char*)d_ws;
    unsigned short* xnb = (unsigned short*)w;                        // 16 MB
    unsigned short* ynb = (unsigned short*)(w + 16777216);           // 16 MB
    float* us   = (float*)(w + 2 * 16777216);                        // 64 KB
    float* vs   = (float*)(w + 2 * 16777216 + 65536);                // 64 KB
    float* errb = (float*)(w + 2 * 16777216 + 2 * 65536);            // 512 B
    int*   bar  = (int*)(w + 2 * 16777216 + 2 * 65536 + 512);        // 256 B

    float* cost = out;                    // 8
    float* pi   = out + 32776;            // 33554432
    float* Cout = out + 33587208;         // 33554432
    // G/GT live in the pi region until the final kernel overwrites it
    unsigned short* Gh  = (unsigned short*)pi;
    unsigned short* GTh = Gh + 33554432;

    // Cooperative launch kept purely for the co-residency guarantee; grid
    // sized by occupancy query, capped at the measured-best 512 blocks (R1/R2).
    static int coopGrid = 0;
    if (coopGrid == 0) {
        int nb = 0;
        hipError_t e = hipOccupancyMaxActiveBlocksPerMultiprocessor(
            &nb, (const void*)sinkhorn_kernel, 256, 0);
        if (e != hipSuccess || nb < 1) nb = 2;
        int cus = 256;
        hipDeviceProp_t prop;
        if (hipGetDeviceProperties(&prop, 0) == hipSuccess && prop.multiProcessorCount > 0)
            cus = prop.multiProcessorCount;
        long g = (long)nb * cus;
        if (g > 512) g = 512;                    // measured sweet spot (R1->R2)
        if (g < 64)  g = 64;
        coopGrid = (int)g;
    }

    norm_cast_kernel<<<8192, 256, 0, stream>>>(x, y, xnb, ynb, out, us, vs, errb, bar);
    gemm_kernel<<<2048, 256, 0, stream>>>(xnb, ynb, Cout, (_Float16*)Gh, (_Float16*)GTh);

    const _Float16* Gc  = (const _Float16*)Gh;
    const _Float16* GTc = (const _Float16*)GTh;
    void* cargs[] = { (void*)&Gc, (void*)&GTc, (void*)&us, (void*)&vs,
                      (void*)&errb, (void*)&bar };
    hipLaunchCooperativeKernel((void*)sinkhorn_kernel, dim3(coopGrid), dim3(256),
                               cargs, 0, stream);

    pi_cost_kernel<<<16384, 256, 0, stream>>>(Cout, us, vs, pi, cost);
}

// Round 5
// 600.462 us; speedup vs baseline: 1.7556x; 1.2549x over previous
//
#include <hip/hip_runtime.h>
#include <hip/hip_fp16.h>
#include <hip/hip_cooperative_groups.h>

typedef __attribute__((ext_vector_type(8))) short bf16x8;
typedef __attribute__((ext_vector_type(4))) float f32x4;
typedef __attribute__((ext_vector_type(8))) _Float16 half8;
typedef __attribute__((ext_vector_type(4))) _Float16 half4;

// Problem constants: B=8, N=M=2048, D=512, eps=0.1, max_iter=100, thresh=0.1
// d_out layout (floats): cost[8] | mu[16384] | nu[16384] | pi[33554432] | C[33554432]
// pi region doubles as G (=-C/eps, fp16) + GT (transpose) until the final kernel.

// ---------------- normalize + bf16 cast + state init ----------------
__global__ __launch_bounds__(256) void norm_cast_kernel(
    const float* __restrict__ x, const float* __restrict__ y,
    unsigned short* __restrict__ xnb, unsigned short* __restrict__ ynb,
    float* __restrict__ out, float* __restrict__ us, float* __restrict__ vs,
    float* __restrict__ errb, int* __restrict__ bar)
{
    int tid = blockIdx.x * 256 + threadIdx.x;
    if (tid < 8) out[tid] = 0.0f;                       // cost accumulators
    if (tid < 16384) {
        out[8 + tid]     = 1.0f / 2048.0f;              // mu
        out[16392 + tid] = 1.0f / 2048.0f;              // nu
        us[tid] = 0.0f;                                 // sinkhorn state init here:
        vs[tid] = 0.0f;                                 // saves the bootstrap grid.sync
    }
    if (tid < 128) errb[tid] = 0.0f;
    if (tid < 64)  bar[tid]  = 0;                       // barrier cnt/gen

    int w = tid >> 6;                                   // one wave per row, 32768 rows
    int lane = threadIdx.x & 63;
    const float* src = ((w < 16384) ? x : y) + (size_t)(w & 16383) * 512;
    unsigned short* dst = ((w < 16384) ? xnb : ynb) + (size_t)(w & 16383) * 512;

    float4 a = ((const float4*)src)[lane * 2];
    float4 b = ((const float4*)src)[lane * 2 + 1];
    float ss = a.x*a.x + a.y*a.y + a.z*a.z + a.w*a.w
             + b.x*b.x + b.y*b.y + b.z*b.z + b.w*b.w;
#pragma unroll
    for (int off = 32; off > 0; off >>= 1) ss += __shfl_xor(ss, off);
    float rn = rsqrtf(ss);

    float v[8] = {a.x*rn, a.y*rn, a.z*rn, a.w*rn, b.x*rn, b.y*rn, b.z*rn, b.w*rn};
    unsigned short o[8];
#pragma unroll
    for (int i = 0; i < 8; ++i) {
        unsigned int u = __float_as_uint(v[i]);
        o[i] = (unsigned short)((u + 0x7fffu + ((u >> 16) & 1u)) >> 16);  // RNE to bf16
    }
    unsigned int w0 = (unsigned)o[0] | ((unsigned)o[1] << 16);
    unsigned int w1 = (unsigned)o[2] | ((unsigned)o[3] << 16);
    unsigned int w2 = (unsigned)o[4] | ((unsigned)o[5] << 16);
    unsigned int w3 = (unsigned)o[6] | ((unsigned)o[7] << 16);
    uint4 pk; pk.x = w0; pk.y = w1; pk.z = w2; pk.w = w3;
    *(uint4*)(dst + lane * 8) = pk;
}

// ---------------- batched bf16 MFMA GEMM: C = 1 - xn·ynT ----------------
// Writes C fp32, G fp16 (row-major) AND GT fp16 (transposed, via LDS bounce).
__global__ __launch_bounds__(256) void gemm_kernel(
    const unsigned short* __restrict__ xnb, const unsigned short* __restrict__ ynb,
    float* __restrict__ Cout, _Float16* __restrict__ G, _Float16* __restrict__ GT)
{
    __shared__ __align__(16) unsigned short smem[128 * 136];
    unsigned short* As = smem;
    unsigned short* Bs = smem + 128 * 64;

    int bid = blockIdx.x;
    int b  = bid >> 8;                 // 256 tiles per batch
    int t  = bid & 255;
    int tn = t >> 4, tm = t & 15;      // 128x128 tile coords
    const unsigned short* Abase = xnb + ((size_t)b * 2048 + tn * 128) * 512;
    const unsigned short* Bbase = ynb + ((size_t)b * 2048 + tm * 128) * 512;

    int tid = threadIdx.x;
    int wave = tid >> 6, lane = tid & 63;
    int wr = wave >> 1, wc = wave & 1;
    int quad = lane >> 4, l16 = lane & 15;

    f32x4 acc[4][4] = {};

    for (int k0 = 0; k0 < 512; k0 += 64) {
#pragma unroll
        for (int rr = 0; rr < 4; ++rr) {
            int chunk = rr * 256 + tid;         // 0..1023
            int row = chunk >> 3;               // 0..127
            int gr  = chunk & 7;                // 8-elem granule
            int sgr = gr ^ (row & 7);
            *(uint4*)(As + row * 64 + sgr * 8) =
                *(const uint4*)(Abase + (size_t)row * 512 + k0 + gr * 8);
            *(uint4*)(Bs + row * 64 + sgr * 8) =
                *(const uint4*)(Bbase + (size_t)row * 512 + k0 + gr * 8);
        }
        __syncthreads();
#pragma unroll
        for (int kk = 0; kk < 64; kk += 32) {
            bf16x8 af[4], bfr[4];
            int g = (kk >> 3) + quad;
#pragma unroll
            for (int i = 0; i < 4; ++i) {
                int rowA = wr * 64 + i * 16 + l16;
                af[i] = *(const bf16x8*)(As + rowA * 64 + ((g ^ (rowA & 7)) << 3));
                int rowB = wc * 64 + i * 16 + l16;
                bfr[i] = *(const bf16x8*)(Bs + rowB * 64 + ((g ^ (rowB & 7)) << 3));
            }
#pragma unroll
            for (int i = 0; i < 4; ++i)
#pragma unroll
                for (int j = 0; j < 4; ++j)
                    acc[i][j] = __builtin_amdgcn_mfma_f32_16x16x32_bf16(
                        af[i], bfr[j], acc[i][j], 0, 0, 0);
        }
        __syncthreads();
    }

    // epilogue: C/D layout col=lane&15, row=quad*4+reg
    unsigned short* gt = smem;             // reuse: staging dead, synced above
    size_t cbase = (size_t)b * 2048 * 2048;
#pragma unroll
    for (int i = 0; i < 4; ++i) {
#pragma unroll
        for (int j = 0; j < 4; ++j) {
            int n0l = wr * 64 + i * 16 + quad * 4;   // local n base (multiple of 4)
            int ml  = wc * 64 + j * 16 + l16;        // local m
            int n0 = tn * 128 + n0l;
            int m  = tm * 128 + ml;
            half4 gv;
#pragma unroll
            for (int rg = 0; rg < 4; ++rg) {
                float c = 1.0f - acc[i][j][rg];
                size_t idx = cbase + (size_t)(n0 + rg) * 2048 + m;
                Cout[idx] = c;
                _Float16 gh = (_Float16)(-10.0f * c);   // -C/eps
                G[idx] = gh;
                gv[rg] = gh;
            }
            *(half4*)(gt + ml * 136 + n0l) = gv;     // 8B store, 8B-aligned
        }
    }
    __syncthreads();
#pragma unroll
    for (int k = 0; k < 8; ++k) {
        int chunk = k * 256 + tid;
        int row = chunk >> 4;               // local m 0..127
        int c8  = chunk & 15;               // 8-elem column chunk
        uint4 vv = *(const uint4*)(gt + row * 136 + c8 * 8);
        *(uint4*)((unsigned short*)GT + cbase +
                  (size_t)(tm * 128 + row) * 2048 + tn * 128 + c8 * 8) = vv;
    }
}

// ---------------- cooperative Sinkhorn loop ----------------
__device__ __forceinline__ float row_lse_2048(const _Float16* __restrict__ row,
                                              const float* __restrict__ vec, int lane)
{
    float vals[32];
    float mx = -3.0e38f;
#pragma unroll
    for (int c = 0; c < 4; ++c) {
        int m0 = c * 512 + lane * 8;
        half8 h  = *(const half8*)(row + m0);
        float4 f0 = *(const float4*)(vec + m0);
        float4 f1 = *(const float4*)(vec + m0 + 4);
        float tv[8] = { f0.x + (float)h[0], f0.y + (float)h[1],
                        f0.z + (float)h[2], f0.w + (float)h[3],
                        f1.x + (float)h[4], f1.y + (float)h[5],
                        f1.z + (float)h[6], f1.w + (float)h[7] };
#pragma unroll
        for (int j = 0; j < 8; ++j) { vals[c * 8 + j] = tv[j]; mx = fmaxf(mx, tv[j]); }
    }
#pragma unroll
    for (int off = 32; off > 0; off >>= 1) mx = fmaxf(mx, __shfl_xor(mx, off));
    float s = 0.0f;
#pragma unroll
    for (int i = 0; i < 32; ++i) s += __expf(vals[i] - mx);
#pragma unroll
    for (int off = 32; off > 0; off >>= 1) s += __shfl_xor(s, off);
    return mx + __logf(s);
}

// Lean grid barrier (sense via generation counter). R2->R4 measured: replacing
// cg::sync with this + dropping the bootstrap sync took sinkhorn from 348us
// to <216us (out of top-5). Protocol: cnt reset happens-before gen RELEASE
// bump; barrier k+1 arrivals (only possible after ACQUIRE of gen k+1) see
// cnt=0; spinners never touch cnt. gen monotone in-run, re-zeroed by
// norm_cast each graph replay.
__device__ __forceinline__ void gridbar(int* cnt, int* gen, int nb)
{
    __syncthreads();
    if (threadIdx.x == 0) {
        int g = __hip_atomic_load(gen, __ATOMIC_RELAXED, __HIP_MEMORY_SCOPE_AGENT);
        int v = __hip_atomic_fetch_add(cnt, 1, __ATOMIC_ACQ_REL, __HIP_MEMORY_SCOPE_AGENT);
        if (v == nb - 1) {
            __hip_atomic_store(cnt, 0, __ATOMIC_RELAXED, __HIP_MEMORY_SCOPE_AGENT);
            __hip_atomic_fetch_add(gen, 1, __ATOMIC_RELEASE, __HIP_MEMORY_SCOPE_AGENT);
        } else {
            while (__hip_atomic_load(gen, __ATOMIC_RELAXED, __HIP_MEMORY_SCOPE_AGENT) == g)
                __builtin_amdgcn_s_sleep(1);
            (void)__hip_atomic_load(gen, __ATOMIC_ACQUIRE, __HIP_MEMORY_SCOPE_AGENT);
        }
    }
    __syncthreads();
}

__global__ __launch_bounds__(256, 4) void sinkhorn_kernel(
    const _Float16* __restrict__ G, const _Float16* __restrict__ GT,
    float* __restrict__ us, float* __restrict__ vs, float* __restrict__ errb,
    int* __restrict__ bar)
{
    __shared__ float wred[4];
    int tid = blockIdx.x * 256 + threadIdx.x;
    const float log_mu = logf(1.0f / 2048.0f + 1e-8f);   // == log_nu
    int gwave = tid >> 6;
    int wave  = threadIdx.x >> 6;
    int lane  = threadIdx.x & 63;
    const int nwaves = (gridDim.x * 256) >> 6;           // 512 blocks -> 8 rows/wave
    const int nb = (int)gridDim.x;
    int* cnt = bar;
    int* gen = bar + 32;                                 // separate cacheline

    for (int it = 0; it < 100; ++it) {
        // u-pass: rows of G   (us/vs store the eps-scaled duals u/eps, v/eps)
        float werr = 0.0f;
        for (int r = gwave; r < 16384; r += nwaves) {
            int b = r >> 11;
            float lse = row_lse_2048(G + (size_t)r * 2048, vs + (b << 11), lane);
            float un = log_mu - lse;
            werr += fabsf(un - us[r]);
            if (lane == 0) us[r] = un;
        }
        // block-local reduce -> one atomicAdd per block (4x less contention)
        if (lane == 0) wred[wave] = werr;
        __syncthreads();
        if (threadIdx.x == 0)
            atomicAdd(&errb[it], (wred[0] + wred[1] + wred[2] + wred[3]) * 0.1f);
        gridbar(cnt, gen, nb);
        float err = errb[it] * 0.125f;                   // mean over B=8
        // v-pass: rows of GT (columns of G), uses updated u
        for (int r = gwave; r < 16384; r += nwaves) {
            int b = r >> 11;
            float lse = row_lse_2048(GT + (size_t)r * 2048, us + (b << 11), lane);
            if (lane == 0) vs[r] = log_mu - lse;
        }
        gridbar(cnt, gen, nb);
        if (err < 0.1f) break;  // uniform across grid: same errb value everywhere
    }
}

// ---------------- pi = exp(us + vs - C/eps), cost = sum(pi*C) ----------------
// R4 post-mortem: the 16384-block version sat at 216us / 938 GB/s with every
// pipe idle (VALUBusy 4.8%) -> diagnosis: 16384 end-of-block atomicAdds all
// landing on ONE 32B cacheline (cost[0..7]) serialize at the L2 atomic unit
// (~25-50cy each = 100-200us), plus tiny-block ramp overhead. Fix: 1024
// blocks x 16 rows (each block within one batch: 2048/16=128), 16x more work
// per thread (ILP across rows), one atomicAdd per block -> 1024 atomics,
// 128 per address (~8us worst case). Arithmetic & bytes bit-identical.
__global__ __launch_bounds__(256) void pi_cost_kernel(
    const float* __restrict__ C, const float* __restrict__ us, const float* __restrict__ vs,
    float* __restrict__ pi, float* __restrict__ cost)
{
    __shared__ float red[4];
    int r0 = blockIdx.x * 16;         // 1024 blocks x 16 rows
    int b  = r0 >> 11;
    const float* vb = vs + (b << 11);
    int t = threadIdx.x;
    float csum = 0.0f;
#pragma unroll 2
    for (int i = 0; i < 16; ++i) {
        int r = r0 + i;
        const float* Crow = C + (size_t)r * 2048;
        float* Prow = pi + (size_t)r * 2048;
        float u = us[r];
#pragma unroll
        for (int cch = 0; cch < 2; ++cch) {
            int m0 = (cch * 256 + t) * 4;
            float4 cv = *(const float4*)(Crow + m0);
            float4 vv = *(const float4*)(vb + m0);
            float4 p;
            p.x = __expf(u + vv.x - 10.0f * cv.x);
            p.y = __expf(u + vv.y - 10.0f * cv.y);
            p.z = __expf(u + vv.z - 10.0f * cv.z);
            p.w = __expf(u + vv.w - 10.0f * cv.w);
            *(float4*)(Prow + m0) = p;
            csum += p.x * cv.x + p.y * cv.y + p.z * cv.z + p.w * cv.w;
        }
    }
#pragma unroll
    for (int off = 32; off > 0; off >>= 1) csum += __shfl_xor(csum, off);
    int wave = t >> 6, lane = t & 63;
    if (lane == 0) red[wave] = csum;
    __syncthreads();
    if (t == 0) atomicAdd(&cost[b], red[0] + red[1] + red[2] + red[3]);
}

extern "C" void kernel_launch(void* const* d_in, const int* in_sizes, int n_in,
                              void* d_out, int out_size, void* d_ws, size_t ws_size,
                              hipStream_t stream) {
    const float* x = (const float*)d_in[0];
    const float* y = (const float*)d_in[1];
    float* out = (float*)d_out;

    char* w = (char*)d_ws;
    unsigned short* xnb = (unsigned short*)w;                        // 16 MB
    unsigned short* ynb = (unsigned short*)(w + 16777216);           // 16 MB
    float* us   = (float*)(w + 2 * 16777216);                        // 64 KB
    float* vs   = (float*)(w + 2 * 16777216 + 65536);                // 64 KB
    float* errb = (float*)(w + 2 * 16777216 + 2 * 65536);            // 512 B
    int*   bar  = (int*)(w + 2 * 16777216 + 2 * 65536 + 512);        // 256 B

    float* cost = out;                    // 8
    float* pi   = out + 32776;            // 33554432
    float* Cout = out + 33587208;         // 33554432
    // G/GT live in the pi region until the final kernel overwrites it
    unsigned short* Gh  = (unsigned short*)pi;
    unsigned short* GTh = Gh + 33554432;

    // Cooperative launch kept purely for the co-residency guarantee; grid
    // sized by occupancy query, capped at the measured-best 512 blocks (R1/R2).
    static int coopGrid = 0;
    if (coopGrid == 0) {
        int nb = 0;
        hipError_t e = hipOccupancyMaxActiveBlocksPerMultiprocessor(
            &nb, (const void*)sinkhorn_kernel, 256, 0);
        if (e != hipSuccess || nb < 1) nb = 2;
        int cus = 256;
        hipDeviceProp_t prop;
        if (hipGetDeviceProperties(&prop, 0) == hipSuccess && prop.multiProcessorCount > 0)
            cus = prop.multiProcessorCount;
        long g = (long)nb * cus;
        if (g > 512) g = 512;                    // measured sweet spot (R1->R2)
        if (g < 64)  g = 64;
        coopGrid = (int)g;
    }

    norm_cast_kernel<<<8192, 256, 0, stream>>>(x, y, xnb, ynb, out, us, vs, errb, bar);
    gemm_kernel<<<2048, 256, 0, stream>>>(xnb, ynb, Cout, (_Float16*)Gh, (_Float16*)GTh);

    const _Float16* Gc  = (const _Float16*)Gh;
    const _Float16* GTc = (const _Float16*)GTh;
    void* cargs[] = { (void*)&Gc, (void*)&GTc, (void*)&us, (void*)&vs,
                      (void*)&errb, (void*)&bar };
    hipLaunchCooperativeKernel((void*)sinkhorn_kernel, dim3(coopGrid), dim3(256),
                               cargs, 0, stream);

    pi_cost_kernel<<<1024, 256, 0, stream>>>(Cout, us, vs, pi, cost);
}